// Round 6
// baseline (333.243 us; speedup 1.0000x reference)
//
#include <hip/hip_runtime.h>

// ---------------------------------------------------------------------------
// DiffAttention forward, bf16 MFMA pipeline.  B=4 T=1024 C=1024 H=16 hs=64 dv=128.
//   1. cast x -> bf16; transpose-cast weights -> W^T[n][k] bf16
//   2. proj GEMM: 256x128 tile, BK=64, 512-thr 8-wave (2Mx4N), 2-phase K-loop,
//      dbuf LDS (96 KiB -> 1 blk/CU but grid 768 = EXACTLY 3 rounds, no tail),
//      counted vmcnt (4/2, never 0 mid-loop), T2 both-sides XOR swizzle,
//      T5 setprio, T1 bijective XCD swizzle.  proj[4096][6144] = xb @ wcat^T.
//   3. transpose v slice -> vt[(b,h)][dim][perm(key)]
//   4. attention, SPLIT-STREAM + PAIRED qblk (R5 structure, unchanged).
//   4b. combine: y = a1 - lam_h*a2, subLN over 128, *(1-LI), bf16 -> yln.
//   5. out GEMM: out[4096][1024] fp32 = yln @ wc^T  (BN=64 tiles, 512 blocks)
// MFMA mappings (HW-verified): A[m=lane&15][k=quad*8+j] (K=32) / quad*4+j
// (K=16); B^T[n=lane&15][k=same]; C/D: col=lane&15, row=quad*4+reg.
// R8: #else of MFMA16 guard must be host-safe.
// R10 (R2): no-LDS direct-global attn regressed. Keep LDS staging.
// R13 (R5 post-mortem): ring-4 regressed 77->92 because (a) 384 blk @1/CU =
// 1.5 rounds -> 25% tail loss (Occ 16%<25% cap), (b) swizzle dropped -> 4.7M
// conflicts, (c) 16-MFMA steps too thin.  ALSO: ~4.85cyc/MFMA is PER-CU
// (per-SIMD ~19cyc) -> 256x128 @8 waves is MFMA-bound (1242 vs 640 LDS cyc).
// R6 staging/wait schedule (derived, race-checked):
//   S0(t) = {A rows 0-63,128-191; B rows 0-127} (4 GLDS)  [everything ph0
//   reads: wr0 mhalf0 = rows 0-63, wr1 mhalf0 = 128-191, B all waves]
//   S1(t) = {A rows 64-127,192-255} (2 GLDS)              [ph1's mhalf1]
//   prologue: S0(0),S1(0),S0(1); vmcnt(6) [S0(0) done]; bar.
//   tile t ph0: [t>0: issue S0(t+1)->nxt] reads S0(t); mid vmcnt(4)
//     [outstanding S1(t)+S0(t+1)=6 -> oldest 2 = S1(t) done] + bar.
//   tile t ph1: [issue S1(t+1)] reads S1(t); boundary vmcnt(2)
//     [outstanding S0(t+1)+S1(t+1)=6 -> oldest 4 = S0(t+1) done] + bar.
//   Last tile: mid wait becomes vmcnt(0) (nothing else in flight).
// ---------------------------------------------------------------------------

#define T_SEQ 1024
#define NH 16
#define DV 128
#define NPROJ 6144
#define KSTR 72  // attn K/V LDS row stride (elements)

typedef __bf16 bf16_t;
typedef __bf16 bf16x8 __attribute__((ext_vector_type(8)));
typedef __bf16 bf16x4 __attribute__((ext_vector_type(4)));
typedef __bf16 bf16x2 __attribute__((ext_vector_type(2)));
typedef _Float16 f16x4 __attribute__((ext_vector_type(4)));
typedef _Float16 f16x2 __attribute__((ext_vector_type(2)));
typedef short s16x4 __attribute__((ext_vector_type(4)));
typedef float f32x4 __attribute__((ext_vector_type(4)));

#define LAMBDA_INIT 0.35550906759096928f
#define ONE_MINUS_LI 0.6444909324090307f
#define LOG2E 1.4426950408889634f
// defer-rescale threshold in RAW score units: 8 / (0.125*log2e) ~= 44.36
#define RTHR 44.36f

#if __has_builtin(__builtin_amdgcn_mfma_f32_16x16x16_bf16)
#define MFMA16(a, b, c) __builtin_amdgcn_mfma_f32_16x16x16_bf16(a, b, c, 0, 0, 0)
#elif __has_builtin(__builtin_amdgcn_mfma_f32_16x16x16bf16_1k)
#define MFMA16(a, b, c)                                                       \
  __builtin_amdgcn_mfma_f32_16x16x16bf16_1k(                                  \
      __builtin_bit_cast(s16x4, a), __builtin_bit_cast(s16x4, b), c, 0, 0, 0)
#else
#define MFMA16(a, b, c) (c)  // host pass only — never executed
#endif

#define MFMA32(a, b, c) __builtin_amdgcn_mfma_f32_16x16x32_bf16(a, b, c, 0, 0, 0)

// async global->LDS, 16B/lane.
#define GLDS(g, l)                                                            \
  __builtin_amdgcn_global_load_lds(                                           \
      (const __attribute__((address_space(1))) void*)(g),                     \
      (__attribute__((address_space(3))) void*)(l), 16, 0, 0)

// ---------------- workspace layout (bytes) ----------------
static const size_t OFF_WCAT = 0;                                  // 6144x1024 bf16
static const size_t OFF_XB = OFF_WCAT + (size_t)6144 * 1024 * 2;   // 4096x1024 bf16
static const size_t OFF_WCT = OFF_XB + (size_t)4096 * 1024 * 2;    // 1024x2048 bf16
static const size_t OFF_PROJ = OFF_WCT + (size_t)2048 * 1024 * 2;  // 4096x6144 bf16
static const size_t OFF_VT = OFF_PROJ + (size_t)4096 * 6144 * 2;   // 64*128*1024 bf16
static const size_t OFF_YLN = OFF_VT + (size_t)64 * 128 * 1024 * 2;// 4096x2048 bf16
static const size_t OFF_LAM = OFF_YLN + (size_t)4096 * 2048 * 2;   // 16 f32
// a1 (fp16, 16.78 MB) aliases YLN (combine rewrites in place); a2 aliases
// WCAT+XB (dead after proj GEMM).

// ---------------- elementwise cast x -> bf16 ----------------
__global__ void __launch_bounds__(256) cast_x(const float* __restrict__ x,
                                              bf16_t* __restrict__ o) {
  const int i = (blockIdx.x * 256 + threadIdx.x) * 4;
  float4 v = *(const float4*)(x + i);
  bf16x4 r = {(bf16_t)v.x, (bf16_t)v.y, (bf16_t)v.z, (bf16_t)v.w};
  *(bf16x4*)(o + i) = r;
}

// ---------------- transpose-cast weight W[K][N] fp32 -> Wt[row0+n][k] bf16 ----
__device__ __forceinline__ void tcast_body(const float* __restrict__ W,
                                           bf16_t* __restrict__ Wt, int K,
                                           int N, int row0) {
  __shared__ float tile[32][33];
  const int k0 = blockIdx.x * 32, n0 = blockIdx.y * 32;
  const int tx = threadIdx.x & 31, ty = threadIdx.x >> 5;  // 32x8
#pragma unroll
  for (int i = 0; i < 32; i += 8)
    tile[ty + i][tx] = W[(long)(k0 + ty + i) * N + n0 + tx];
  __syncthreads();
#pragma unroll
  for (int i = 0; i < 32; i += 8)
    Wt[(long)(row0 + n0 + ty + i) * K + k0 + tx] = (bf16_t)tile[tx][ty + i];
}

__global__ void __launch_bounds__(256) tcast_w(const float* __restrict__ W,
                                               bf16_t* __restrict__ Wt, int K,
                                               int N, int row0) {
  tcast_body(W, Wt, K, N, row0);
}

// fused: the four 1024x1024 q/k weights in one launch (z selects)
__global__ void __launch_bounds__(256) tcast_w4(const float* __restrict__ W0,
                                                const float* __restrict__ W1,
                                                const float* __restrict__ W2,
                                                const float* __restrict__ W3,
                                                bf16_t* __restrict__ Wt) {
  const float* Ws[4] = {W0, W1, W2, W3};
  tcast_body(Ws[blockIdx.z], Wt, 1024, 1024, blockIdx.z * 1024);
}

// ---------------- per-head lambda ----------------
__global__ void lam_kernel(const float* __restrict__ lq1,
                           const float* __restrict__ lk1,
                           const float* __restrict__ lq2,
                           const float* __restrict__ lk2,
                           float* __restrict__ lam) {
  const int h = threadIdx.x;
  if (h < NH) {
    float d1 = 0.f, d2 = 0.f;
    for (int i = 0; i < 64; ++i) {
      d1 += lq1[h * 64 + i] * lk1[h * 64 + i];
      d2 += lq2[h * 64 + i] * lk2[h * 64 + i];
    }
    lam[h] = expf(d1) - expf(d2) + LAMBDA_INIT;
  }
}

// ---------------- proj GEMM: 256x128 tile, 2-phase counted-vmcnt pipeline ---
// C[M][N] bf16 = A[M][K] @ Bt[N][K]^T.  See header for the schedule proof.
// T2 swizzle: LDS granule (row, g) holds global granule g^(row&7); reads use
// byte addr row*128 + ((kh*4+quad)^(l16&7))*16  (row&7==l16&7 for all frags).
#define GBM 256
#define GBN 128
#define GBK 64

// stage batches for K-tile tt into buffer buf (dest linear, src pre-swizzled)
#define STAGE_S0(buf, tt)                                                     \
  {                                                                           \
    const long kk_ = (long)(tt)*GBK;                                          \
    GLDS(gA + kk_, (bf16_t*)((char*)As[buf] + tid * 16));                     \
    GLDS(gA + (long)128 * K + kk_,                                            \
         (bf16_t*)((char*)As[buf] + 16384 + tid * 16));                       \
    GLDS(gB + kk_, (bf16_t*)((char*)Bs[buf] + tid * 16));                     \
    GLDS(gB + (long)64 * K + kk_,                                             \
         (bf16_t*)((char*)Bs[buf] + 8192 + tid * 16));                        \
  }
#define STAGE_S1(buf, tt)                                                     \
  {                                                                           \
    const long kk_ = (long)(tt)*GBK;                                          \
    GLDS(gA + (long)64 * K + kk_,                                             \
         (bf16_t*)((char*)As[buf] + 8192 + tid * 16));                        \
    GLDS(gA + (long)192 * K + kk_,                                            \
         (bf16_t*)((char*)As[buf] + 24576 + tid * 16));                       \
  }

__global__ void __launch_bounds__(512, 1) gemm256(const bf16_t* __restrict__ A,
                                                  const bf16_t* __restrict__ Bt,
                                                  bf16_t* __restrict__ C,
                                                  int M, int N, int K,
                                                  int nbx) {
  __shared__ __align__(16) bf16_t As[2][GBM * GBK];  // [256][64] per buf
  __shared__ __align__(16) bf16_t Bs[2][GBN * GBK];  // [128][64] per buf
  const int tid = threadIdx.x;
  const int w = tid >> 6, lane = tid & 63;
  const int quad = lane >> 4, l16 = lane & 15;
  const int wr = w >> 2, wc = w & 3;  // 2M x 4N; wave tile 128x32

  // ---- bijective XCD swizzle (grid % 8 == 0) ----
  const int wg = blockIdx.x;
  const int cpx = gridDim.x >> 3;
  const int sw = (wg & 7) * cpx + (wg >> 3);
  const int by = sw / nbx, bx = sw % nbx;
  const int m0 = by * GBM, n0 = bx * GBN;

  // ---- staging source (pre-swizzled granule) ----
  const int rp = tid >> 3;                       // row within 64-row pass
  const int gsrc = ((tid & 7) ^ (rp & 7)) * 8;   // swizzled granule (elems)
  const bf16_t* gA = A + (long)(m0 + rp) * K + gsrc;
  const bf16_t* gB = Bt + (long)(n0 + rp) * K + gsrc;

  // ---- swizzled read byte-offsets (per-lane constants) ----
  const int sx = l16 & 7;
  const int ko0 = (quad ^ sx) * 16;        // kh=0 (k 0..31)
  const int ko1 = ((4 + quad) ^ sx) * 16;  // kh=1 (k 32..63)

  f32x4 acc[8][2] = {};  // [mh*4+mt][nt]
  const int ntk = K >> 6;  // 16

  // ---- prologue ----
  STAGE_S0(0, 0);
  STAGE_S1(0, 0);
  STAGE_S0(1, 1);
  asm volatile("s_waitcnt vmcnt(6)" ::: "memory");
  __builtin_amdgcn_s_barrier();
  __builtin_amdgcn_sched_barrier(0);

  for (int t = 0; t < ntk; ++t) {
    const int cur = t & 1, nxt = cur ^ 1;
    const char* Ab = (const char*)As[cur] + (size_t)(wr * 128 + l16) * 128;
    const char* Bb = (const char*)Bs[cur] + (size_t)(wc * 32 + l16) * 128;

    // ---------------- phase 0: mhalf0 x all-B ----------------
    if (t > 0 && t + 1 < ntk) STAGE_S0(nxt, t + 1);
    bf16x8 af[4][2], bfv[2][2];
#pragma unroll
    for (int mt = 0; mt < 4; ++mt) {
      af[mt][0] = *(const bf16x8*)(Ab + (size_t)mt * 2048 + ko0);
      af[mt][1] = *(const bf16x8*)(Ab + (size_t)mt * 2048 + ko1);
    }
#pragma unroll
    for (int n = 0; n < 2; ++n) {
      bfv[n][0] = *(const bf16x8*)(Bb + (size_t)n * 2048 + ko0);
      bfv[n][1] = *(const bf16x8*)(Bb + (size_t)n * 2048 + ko1);
    }
    asm volatile("s_waitcnt lgkmcnt(0)" ::: "memory");
    __builtin_amdgcn_sched_barrier(0);
    __builtin_amdgcn_s_setprio(1);
#pragma unroll
    for (int mt = 0; mt < 4; ++mt)
#pragma unroll
      for (int n = 0; n < 2; ++n) {
        acc[mt][n] = MFMA32(af[mt][0], bfv[n][0], acc[mt][n]);
        acc[mt][n] = MFMA32(af[mt][1], bfv[n][1], acc[mt][n]);
      }
    __builtin_amdgcn_s_setprio(0);
    // mid wait: S1(t) landed (see header proof)
    if (t + 1 < ntk) {
      asm volatile("s_waitcnt vmcnt(4)" ::: "memory");
    } else {
      asm volatile("s_waitcnt vmcnt(0)" ::: "memory");
    }
    __builtin_amdgcn_s_barrier();
    __builtin_amdgcn_sched_barrier(0);

    // ---------------- phase 1: mhalf1 x all-B ----------------
    if (t + 1 < ntk) STAGE_S1(nxt, t + 1);
    bf16x8 ag[4][2];
#pragma unroll
    for (int mt = 0; mt < 4; ++mt) {
      ag[mt][0] = *(const bf16x8*)(Ab + 8192 + (size_t)mt * 2048 + ko0);
      ag[mt][1] = *(const bf16x8*)(Ab + 8192 + (size_t)mt * 2048 + ko1);
    }
    asm volatile("s_waitcnt lgkmcnt(0)" ::: "memory");
    __builtin_amdgcn_sched_barrier(0);
    __builtin_amdgcn_s_setprio(1);
#pragma unroll
    for (int mt = 0; mt < 4; ++mt)
#pragma unroll
      for (int n = 0; n < 2; ++n) {
        acc[4 + mt][n] = MFMA32(ag[mt][0], bfv[n][0], acc[4 + mt][n]);
        acc[4 + mt][n] = MFMA32(ag[mt][1], bfv[n][1], acc[4 + mt][n]);
      }
    __builtin_amdgcn_s_setprio(0);
    // boundary wait: S0(t+1) landed
    if (t + 1 < ntk) {
      asm volatile("s_waitcnt vmcnt(2)" ::: "memory");
    }
    __builtin_amdgcn_s_barrier();
    __builtin_amdgcn_sched_barrier(0);
  }

  // ---- epilogue: C-write ----
#pragma unroll
  for (int am = 0; am < 8; ++am)
#pragma unroll
    for (int n = 0; n < 2; ++n) {
      const int col = n0 + wc * 32 + n * 16 + l16;
      const int rbase = m0 + wr * 128 + (am >> 2) * 64 + (am & 3) * 16 + quad * 4;
#pragma unroll
      for (int i = 0; i < 4; ++i)
        C[(long)(rbase + i) * N + col] = (bf16_t)acc[am][n][i];
    }
}

// ---------------- GEMM, BN=64 m97-style (out: M=4096 N=1024 -> 512 blocks) --
#define BM 128
#define BK 32

template <typename OutT>
__global__ void __launch_bounds__(256) gemm_bt_n64(const bf16_t* __restrict__ A,
                                                   const bf16_t* __restrict__ Bt,
                                                   OutT* __restrict__ C, int M,
                                                   int N, int K) {
  __shared__ __align__(16) bf16_t As[BM * BK];
  __shared__ __align__(16) bf16_t Bs[64 * BK];
  const int tid = threadIdx.x;
  const int w = tid >> 6;
  const int lane = tid & 63;
  const int quad = lane >> 4, l16 = lane & 15;
  const int m0 = blockIdx.y * BM, n0 = blockIdx.x * 64;
  const int wm = (w >> 1) * 64, wn = (w & 1) * 32;
  const int srow = tid >> 2;       // 0..63
  const int scol = (tid & 3) * 8;  // 0,8,16,24

  const bf16_t* Ag0 = A + (long)(m0 + srow) * K + scol;
  const bf16_t* Ag1 = Ag0 + (long)64 * K;
  const bf16_t* Bg0 = Bt + (long)(n0 + srow) * K + scol;
  bf16_t* lA0 = As + tid * 8;
  bf16_t* lA1 = As + 2048 + tid * 8;
  bf16_t* lB0 = Bs + tid * 8;

  f32x4 acc[4][2] = {};

  for (int k0 = 0; k0 < K; k0 += BK) {
    GLDS(Ag0 + k0, lA0);
    GLDS(Ag1 + k0, lA1);
    GLDS(Bg0 + k0, lB0);
    __syncthreads();
    bf16x8 af[4], bfr[2];
#pragma unroll
    for (int t = 0; t < 4; ++t)
      af[t] = *(const bf16x8*)(As + (wm + t * 16 + l16) * BK + quad * 8);
#pragma unroll
    for (int t = 0; t < 2; ++t)
      bfr[t] = *(const bf16x8*)(Bs + (wn + t * 16 + l16) * BK + quad * 8);
#pragma unroll
    for (int mt = 0; mt < 4; ++mt)
#pragma unroll
      for (int ntt = 0; ntt < 2; ++ntt)
        acc[mt][ntt] = MFMA32(af[mt], bfr[ntt], acc[mt][ntt]);
    __syncthreads();
  }

#pragma unroll
  for (int mt = 0; mt < 4; ++mt)
#pragma unroll
    for (int ntt = 0; ntt < 2; ++ntt) {
      const int col = n0 + wn + ntt * 16 + l16;
#pragma unroll
      for (int i = 0; i < 4; ++i) {
        const int row = m0 + wm + mt * 16 + quad * 4 + i;
        C[(long)row * N + col] = (OutT)acc[mt][ntt][i];
      }
    }
}

// ---------------- transpose v slice of proj -> vt[(b,h)][d][perm(key)] -------
// Key permutation within each 64-key window (R2-HW-verified): element j of a
// b128 at in-window offset cp*32+quad*8 is key cp*32 + (j>>2)*16 + quad*4 +
// (j&3).
__global__ void __launch_bounds__(256) transpose_v(const bf16_t* __restrict__ proj,
                                                   bf16_t* __restrict__ vt) {
  __shared__ bf16_t tile[32][34];
  const int bh = blockIdx.z;
  const int b = bh >> 4, h = bh & 15;
  const int t0 = blockIdx.x * 32, d0 = blockIdx.y * 32;
  const int tx = threadIdx.x & 31, ty = threadIdx.x >> 5;
  const bf16_t* src = proj + (long)(b * T_SEQ) * NPROJ + 4096 + h * 128;
#pragma unroll
  for (int i = 0; i < 32; i += 8)
    tile[ty + i][tx] = src[(long)(t0 + ty + i) * NPROJ + d0 + tx];
  __syncthreads();
  const int d_loc = threadIdx.x >> 3;
  const int g = threadIdx.x & 7;
  const int s = g >> 2, qd = g & 3;
  const int tl = s * 16 + qd * 4;
  bf16x4 o = {tile[tl + 0][d_loc], tile[tl + 1][d_loc], tile[tl + 2][d_loc],
              tile[tl + 3][d_loc]};
  bf16_t* dst = vt + (long)bh * (DV * T_SEQ) + (long)(d0 + d_loc) * T_SEQ;
  *(bf16x4*)(dst + t0 + qd * 8 + s * 4) = o;
}

// ---------------- attention: split-stream, PAIRED qblk (equal work) ---------
// grid: (1024). x -> p = x>>7 (pair 0..7), st = (x>>6)&1, bh = x&63.
// Phase 0: qblk=15-p, phase 1: qblk=p -> every block runs exactly 17 tiles.
__global__ void __launch_bounds__(256) attn_kernel(const bf16_t* __restrict__ proj,
                                                   const bf16_t* __restrict__ vt,
                                                   _Float16* __restrict__ a1,
                                                   _Float16* __restrict__ a2) {
  const int x = blockIdx.x;
  const int p = x >> 7;
  const int st = (x >> 6) & 1;
  const int bh = x & 63;
  const int b = bh >> 4, h = bh & 15;
  const int tid = threadIdx.x;
  const int w = tid >> 6, lane = tid & 63;
  const int quad = lane >> 4, l16 = lane & 15;
  const long bT = (long)b * T_SEQ;

  __shared__ __align__(16) bf16_t Ks[64 * KSTR];  // [key][dim]
  __shared__ __align__(16) bf16_t Vs[DV * KSTR];  // [dim][perm(key)]

  const int koff = h * 64 + 2048 + st * 1024;
  const bf16_t* gK = proj + (bT + (tid >> 2)) * (long)NPROJ + koff + (tid & 3) * 16;
  const bf16_t* gV = vt + (long)bh * DV * T_SEQ + (long)(tid >> 1) * T_SEQ +
                     (tid & 1) * 32;
  const int kwK = (tid >> 2) * KSTR + (tid & 3) * 16;
  const int kwV = (tid >> 1) * KSTR + (tid & 1) * 32;

  const float sc = 0.125f * LOG2E;
  const bf16x4 one4 = {(bf16_t)1.0f, (bf16_t)1.0f, (bf16_t)1.0f, (bf16_t)1.0f};

  for (int ph = 0; ph < 2; ++ph) {
    const int qblk = ph ? p : 15 - p;
    const int q0 = qblk * 64 + w * 16;
    const int qg = q0 + l16;

    const bf16_t* qrow = proj + (bT + qg) * (long)NPROJ + h * 64 + st * 1024;
    bf16x8 aq[2];
    aq[0] = *(const bf16x8*)(qrow + quad * 8);
    aq[1] = *(const bf16x8*)(qrow + 32 + quad * 8);

    f32x4 O[8] = {};
    float m = -3.0e38f, l = 0.f;

    const int kend_blk = qblk * 64 + 64;
    const int kend_w = q0 + 16;

    bf16x8 rK[2], rV[4];
    rK[0] = *(const bf16x8*)(gK);
    rK[1] = *(const bf16x8*)(gK + 8);
#pragma unroll
    for (int j = 0; j < 4; ++j) rV[j] = *(const bf16x8*)(gV + j * 8);

    for (int kt = 0; kt < kend_blk; kt += 64) {
      *(bf16x8*)(Ks + kwK) = rK[0];
      *(bf16x8*)(Ks + kwK + 8) = rK[1];
#pragma unroll
      for (int j = 0; j < 4; ++j) *(bf16x8*)(Vs + kwV + j * 8) = rV[j];
      __syncthreads();

      if (kt + 64 < kend_blk) {
        const long ko = (long)(kt + 64) * NPROJ;
        rK[0] = *(const bf16x8*)(gK + ko);
        rK[1] = *(const bf16x8*)(gK + ko + 8);
#pragma unroll
        for (int j = 0; j < 4; ++j)
          rV[j] = *(const bf16x8*)(gV + kt + 64 + j * 8);
      }

      if (kt < kend_w) {
        f32x4 s[4];
#pragma unroll
        for (int c = 0; c < 4; ++c) {
          const bf16_t* kr = Ks + (c * 16 + l16) * KSTR;
          bf16x8 ka0 = *(const bf16x8*)(kr + quad * 8);
          bf16x8 ka1 = *(const bf16x8*)(kr + 32 + quad * 8);
          f32x4 z = {};
          z = MFMA32(ka0, aq[0], z);
          z = MFMA32(ka1, aq[1], z);
          s[c] = z;
        }
        if (kt + 63 > q0) {
#pragma unroll
          for (int c = 0; c < 4; ++c)
#pragma unroll
            for (int i = 0; i < 4; ++i) {
              const int key = kt + c * 16 + quad * 4 + i;
              if (key > qg) s[c][i] = -1e30f;
            }
        }
        float t[4];
#pragma unroll
        for (int c = 0; c < 4; ++c)
          t[c] = fmaxf(fmaxf(s[c][0], s[c][1]), fmaxf(s[c][2], s[c][3]));
        float mx = fmaxf(fmaxf(t[0], t[1]), fmaxf(t[2], t[3]));
        mx = fmaxf(mx, __shfl_xor(mx, 16));
        mx = fmaxf(mx, __shfl_xor(mx, 32));
        if (!__all(mx <= m + RTHR)) {
          const float mn = fmaxf(m, mx);
          const float al = exp2f((m - mn) * sc);
          m = mn;
#pragma unroll
          for (int f = 0; f < 8; ++f)
#pragma unroll
            for (int i = 0; i < 4; ++i) O[f][i] *= al;
          l *= al;
        }
        const float ms = m * sc;
        bf16x4 pc[4];
#pragma unroll
        for (int c = 0; c < 4; ++c)
#pragma unroll
          for (int i = 0; i < 4; ++i)
            pc[c][i] = (bf16_t)exp2f(fmaf(s[c][i], sc, -ms));
        f32x4 la = {};
#pragma unroll
        for (int c = 0; c < 4; ++c) la = MFMA16(one4, pc[c], la);
#pragma unroll
        for (int cp = 0; cp < 2; ++cp) {
#pragma unroll
          for (int f = 0; f < 8; ++f) {
            bf16x8 va = *(const bf16x8*)(Vs + (f * 16 + l16) * KSTR +
                                         cp * 32 + quad * 8);
            bf16x4 lo = __builtin_shufflevector(va, va, 0, 1, 2, 3);
            bf16x4 hi = __builtin_shufflevector(va, va, 4, 5, 6, 7);
            O[f] = MFMA16(lo, pc[2 * cp], O[f]);
            O[f] = MFMA16(hi, pc[2 * cp + 1], O[f]);
          }
        }
        l += la[0];
      }
      __syncthreads();
    }

    const float inv = 1.0f / l;
    _Float16* ob = st ? a2 : a1;
    _Float16* dst = ob + ((bT + qg) * 16 + h) * (long)128 + quad * 4;
#pragma unroll
    for (int f = 0; f < 8; ++f) {
      f16x4 o = {(_Float16)(O[f][0] * inv), (_Float16)(O[f][1] * inv),
                 (_Float16)(O[f][2] * inv), (_Float16)(O[f][3] * inv)};
      *(f16x4*)(dst + f * 16) = o;
    }
  }
}

// ---------------- combine: y = a1 - lam*a2, subLN(128), *(1-LI) -> bf16 ------
__global__ void __launch_bounds__(256) combine_kernel(const _Float16* __restrict__ a1,
                                                      const _Float16* __restrict__ a2,
                                                      const float* __restrict__ lamp,
                                                      bf16_t* __restrict__ yln) {
  const int unit = blockIdx.x * 4 + (threadIdx.x >> 6);  // 0..65535 = r*16+h
  const int lane = threadIdx.x & 63;
  const float lam = lamp[unit & 15];
  const long base = (long)unit * 128 + lane * 2;
  f16x2 v1 = *(const f16x2*)(a1 + base);
  f16x2 v2 = *(const f16x2*)(a2 + base);
  float y0 = (float)v1[0] - lam * (float)v2[0];
  float y1 = (float)v1[1] - lam * (float)v2[1];
  float sm = y0 + y1, sq = y0 * y0 + y1 * y1;
#pragma unroll
  for (int off = 1; off < 64; off <<= 1) {
    sm += __shfl_xor(sm, off);
    sq += __shfl_xor(sq, off);
  }
  const float mu = sm * (1.0f / 128.0f);
  const float var = sq * (1.0f / 128.0f) - mu * mu;
  const float rs = rsqrtf(var + 1e-5f) * ONE_MINUS_LI;
  bf16x2 o = {(bf16_t)((y0 - mu) * rs), (bf16_t)((y1 - mu) * rs)};
  *(bf16x2*)(yln + base) = o;
}

// ---------------------------------------------------------------------------
extern "C" void kernel_launch(void* const* d_in, const int* in_sizes, int n_in,
                              void* d_out, int out_size, void* d_ws,
                              size_t ws_size, hipStream_t stream) {
  const float* x = (const float*)d_in[0];
  const float* Wq1 = (const float*)d_in[1];
  const float* Wq2 = (const float*)d_in[2];
  const float* Wk1 = (const float*)d_in[3];
  const float* Wk2 = (const float*)d_in[4];
  const float* Wv = (const float*)d_in[5];
  const float* Wc = (const float*)d_in[6];
  const float* lq1 = (const float*)d_in[7];
  const float* lk1 = (const float*)d_in[8];
  const float* lq2 = (const float*)d_in[9];
  const float* lk2 = (const float*)d_in[10];
  float* out = (float*)d_out;

  char* ws = (char*)d_ws;
  bf16_t* wcat = (bf16_t*)(ws + OFF_WCAT);
  bf16_t* xb = (bf16_t*)(ws + OFF_XB);
  bf16_t* wct = (bf16_t*)(ws + OFF_WCT);
  bf16_t* projb = (bf16_t*)(ws + OFF_PROJ);
  bf16_t* vtb = (bf16_t*)(ws + OFF_VT);
  bf16_t* ylnb = (bf16_t*)(ws + OFF_YLN);
  float* lamp = (float*)(ws + OFF_LAM);
  _Float16* a1b = (_Float16*)(ws + OFF_YLN);   // aliases yln (in-place combine)
  _Float16* a2b = (_Float16*)(ws + OFF_WCAT);  // aliases wcat+xb (dead after proj)

  cast_x<<<4096, 256, 0, stream>>>(x, xb);
  tcast_w4<<<dim3(32, 32, 4), 256, 0, stream>>>(Wq1, Wq2, Wk1, Wk2, wcat);
  tcast_w<<<dim3(32, 64), 256, 0, stream>>>(Wv, wcat, 1024, 2048, 4096);
  tcast_w<<<dim3(64, 32), 256, 0, stream>>>(Wc, wct, 2048, 1024, 0);
  lam_kernel<<<1, 64, 0, stream>>>(lq1, lk1, lq2, lk2, lamp);

  // proj = xb @ wcat^T : M=4096 N=6144 K=1024 ; 16x48 = 768 tiles = 3 exact
  // rounds of 256 CUs (zero tail), 768%8==0 for the XCD swizzle.
  gemm256<<<dim3(768), 512, 0, stream>>>(xb, wcat, projb, 4096, 6144, 1024, 48);
  transpose_v<<<dim3(32, 4, 64), 256, 0, stream>>>(projb, vtb);
  attn_kernel<<<dim3(1024), 256, 0, stream>>>(projb, vtb, a1b, a2b);
  combine_kernel<<<dim3(16384), 256, 0, stream>>>(a1b, a2b, lamp, ylnb);
  // out = yln @ wc^T : M=4096 N=1024 K=2048  (BN=64 -> 512 blocks)
  gemm_bt_n64<float><<<dim3(16, 32), 256, 0, stream>>>(ylnb, wct, out, 4096, 1024, 2048);
}

// Round 8
// 316.698 us; speedup vs baseline: 1.0522x; 1.0522x over previous
//
#include <hip/hip_runtime.h>

// ---------------------------------------------------------------------------
// DiffAttention forward, bf16 MFMA pipeline.  B=4 T=1024 C=1024 H=16 hs=64 dv=128.
//   1. cast x -> bf16; transpose-cast weights -> W^T[n][k] bf16
//   2. proj GEMM: R4 gemm256 (256x256, BK=64, 8 waves, 4-phase, T2 swizzle,
//      vmcnt(0) boundary) — best MEASURED proj (~72us). R5 ring & R6 2-phase
//      both regressed; see R14 lesson.
//   3. transpose v slice -> vt[(b,h)][dim][perm(key)]
//   4. attention, SPLIT-STREAM + PAIRED qblk (R5 structure) with V-staging
//      remapped to 8-rows x 8-granules (bank-uniform writes).
//   4b. combine: y = a1 - lam_h*a2, subLN over 128, *(1-LI), bf16 -> yln.
//   5. out GEMM: gemm_bt BN=128 (ratio-2.0 economics, 256 blocks = 1 round).
// MFMA mappings (HW-verified): A[m=lane&15][k=quad*8+j] (K=32) / quad*4+j
// (K=16); B^T[n=lane&15][k=same]; C/D: col=lane&15, row=quad*4+reg.
// R8: #else of MFMA16 guard must be host-safe.
// R10 (R2): no-LDS direct-global attn regressed. Keep LDS staging.
// R13 (R5): 1-block/CU grids must be multiples of 256 or pay tail.
// R14 (R6): LDS-read ECONOMICS gate the GEMM: per K32-step ratio
// mt*nt/(mt+nt) must be >= ~2.5 (12cyc/b128 vs 4.85cyc/MFMA at CU level).
// 256x256/wave128x64 = 2.67 OK; 256x128/wave128x32 = 1.6 -> LDS-bound
// (R6: MfmaUtil 20, conflicts 0, still slow). Don't shrink wave tiles.
// R15: attn staging-WRITE banks: (tid>>1)-row V mapping puts lanes
// {r,r+8,r+16,r+24} on one bank (4-way); (tid>>3)-row x (tid&7)-granule
// mapping is uniform. Reads were uniform.
// R16 (this round): R7 bench was an infra failure (container died twice) —
// resubmitting the identical kernel; R7's predictions remain untested.
// ---------------------------------------------------------------------------

#define T_SEQ 1024
#define NH 16
#define DV 128
#define NPROJ 6144
#define KSTR 72  // attn K/V LDS row stride (elements)

typedef __bf16 bf16_t;
typedef __bf16 bf16x8 __attribute__((ext_vector_type(8)));
typedef __bf16 bf16x4 __attribute__((ext_vector_type(4)));
typedef __bf16 bf16x2 __attribute__((ext_vector_type(2)));
typedef _Float16 f16x4 __attribute__((ext_vector_type(4)));
typedef _Float16 f16x2 __attribute__((ext_vector_type(2)));
typedef short s16x4 __attribute__((ext_vector_type(4)));
typedef float f32x4 __attribute__((ext_vector_type(4)));

#define LAMBDA_INIT 0.35550906759096928f
#define ONE_MINUS_LI 0.6444909324090307f
#define LOG2E 1.4426950408889634f
// defer-rescale threshold in RAW score units: 8 / (0.125*log2e) ~= 44.36
#define RTHR 44.36f

#if __has_builtin(__builtin_amdgcn_mfma_f32_16x16x16_bf16)
#define MFMA16(a, b, c) __builtin_amdgcn_mfma_f32_16x16x16_bf16(a, b, c, 0, 0, 0)
#elif __has_builtin(__builtin_amdgcn_mfma_f32_16x16x16bf16_1k)
#define MFMA16(a, b, c)                                                       \
  __builtin_amdgcn_mfma_f32_16x16x16bf16_1k(                                  \
      __builtin_bit_cast(s16x4, a), __builtin_bit_cast(s16x4, b), c, 0, 0, 0)
#else
#define MFMA16(a, b, c) (c)  // host pass only — never executed
#endif

#define MFMA32(a, b, c) __builtin_amdgcn_mfma_f32_16x16x32_bf16(a, b, c, 0, 0, 0)

// async global->LDS, 16B/lane.
#define GLDS(g, l)                                                            \
  __builtin_amdgcn_global_load_lds(                                           \
      (const __attribute__((address_space(1))) void*)(g),                     \
      (__attribute__((address_space(3))) void*)(l), 16, 0, 0)

// ---------------- workspace layout (bytes) ----------------
static const size_t OFF_WCAT = 0;                                  // 6144x1024 bf16
static const size_t OFF_XB = OFF_WCAT + (size_t)6144 * 1024 * 2;   // 4096x1024 bf16
static const size_t OFF_WCT = OFF_XB + (size_t)4096 * 1024 * 2;    // 1024x2048 bf16
static const size_t OFF_PROJ = OFF_WCT + (size_t)2048 * 1024 * 2;  // 4096x6144 bf16
static const size_t OFF_VT = OFF_PROJ + (size_t)4096 * 6144 * 2;   // 64*128*1024 bf16
static const size_t OFF_YLN = OFF_VT + (size_t)64 * 128 * 1024 * 2;// 4096x2048 bf16
static const size_t OFF_LAM = OFF_YLN + (size_t)4096 * 2048 * 2;   // 16 f32
// a1 (fp16, 16.78 MB) aliases YLN (combine rewrites in place); a2 aliases
// WCAT+XB (dead after proj GEMM).

// ---------------- elementwise cast x -> bf16 ----------------
__global__ void __launch_bounds__(256) cast_x(const float* __restrict__ x,
                                              bf16_t* __restrict__ o) {
  const int i = (blockIdx.x * 256 + threadIdx.x) * 4;
  float4 v = *(const float4*)(x + i);
  bf16x4 r = {(bf16_t)v.x, (bf16_t)v.y, (bf16_t)v.z, (bf16_t)v.w};
  *(bf16x4*)(o + i) = r;
}

// ---------------- transpose-cast weight W[K][N] fp32 -> Wt[row0+n][k] bf16 ----
__device__ __forceinline__ void tcast_body(const float* __restrict__ W,
                                           bf16_t* __restrict__ Wt, int K,
                                           int N, int row0) {
  __shared__ float tile[32][33];
  const int k0 = blockIdx.x * 32, n0 = blockIdx.y * 32;
  const int tx = threadIdx.x & 31, ty = threadIdx.x >> 5;  // 32x8
#pragma unroll
  for (int i = 0; i < 32; i += 8)
    tile[ty + i][tx] = W[(long)(k0 + ty + i) * N + n0 + tx];
  __syncthreads();
#pragma unroll
  for (int i = 0; i < 32; i += 8)
    Wt[(long)(row0 + n0 + ty + i) * K + k0 + tx] = (bf16_t)tile[tx][ty + i];
}

__global__ void __launch_bounds__(256) tcast_w(const float* __restrict__ W,
                                               bf16_t* __restrict__ Wt, int K,
                                               int N, int row0) {
  tcast_body(W, Wt, K, N, row0);
}

// fused: the four 1024x1024 q/k weights in one launch (z selects)
__global__ void __launch_bounds__(256) tcast_w4(const float* __restrict__ W0,
                                                const float* __restrict__ W1,
                                                const float* __restrict__ W2,
                                                const float* __restrict__ W3,
                                                bf16_t* __restrict__ Wt) {
  const float* Ws[4] = {W0, W1, W2, W3};
  tcast_body(Ws[blockIdx.z], Wt, 1024, 1024, blockIdx.z * 1024);
}

// ---------------- per-head lambda ----------------
__global__ void lam_kernel(const float* __restrict__ lq1,
                           const float* __restrict__ lk1,
                           const float* __restrict__ lq2,
                           const float* __restrict__ lk2,
                           float* __restrict__ lam) {
  const int h = threadIdx.x;
  if (h < NH) {
    float d1 = 0.f, d2 = 0.f;
    for (int i = 0; i < 64; ++i) {
      d1 += lq1[h * 64 + i] * lk1[h * 64 + i];
      d2 += lq2[h * 64 + i] * lk2[h * 64 + i];
    }
    lam[h] = expf(d1) - expf(d2) + LAMBDA_INIT;
  }
}

// ---------------- proj GEMM: R4 256x256 4-phase (measured-best) -------------
// C[M][N] bf16 = A[M][K] @ Bt[N][K]^T.  grid.x = (M/256)*(N/256), %8 == 0.
// LDS: 2 K-tile buffers (A 256x64 + B 256x64 each) = 128 KiB.  Staging for
// tile t+1 goes into buf^1, issued in phases 0-1, drained by ONE vmcnt(0)+
// barrier at the tile boundary.  T2 swizzle: LDS granule g of row r holds
// global granule g^(r&7); reads XOR the byte offset with (l16&7)<<4.
#define GBM 256
#define GBN 256
#define GBK 64

__global__ void __launch_bounds__(512, 1) gemm256(const bf16_t* __restrict__ A,
                                                  const bf16_t* __restrict__ Bt,
                                                  bf16_t* __restrict__ C,
                                                  int M, int N, int K,
                                                  int nbx) {
  __shared__ __align__(16) bf16_t As[2][GBM * GBK];
  __shared__ __align__(16) bf16_t Bs[2][GBN * GBK];
  const int tid = threadIdx.x;
  const int w = tid >> 6, lane = tid & 63;
  const int quad = lane >> 4, l16 = lane & 15;
  const int wr = w >> 2, wc = w & 3;  // 2M x 4N wave grid; wave tile 128x64

  // ---- bijective XCD swizzle (grid % 8 == 0) ----
  const int wg = blockIdx.x;
  const int cpx = gridDim.x >> 3;
  const int sw = (wg & 7) * cpx + (wg >> 3);
  const int by = sw / nbx, bx = sw % nbx;
  const int m0 = by * GBM, n0 = bx * GBN;

  // ---- staging source pointers: lane (r8,g) sources granule g^r8 ----
  const int r8 = lane >> 3, g = lane & 7;
  const int gsw = (g ^ r8) * 8;  // element offset of swizzled 16B granule
  const bf16_t* gA[4];
  const bf16_t* gB[4];
#pragma unroll
  for (int j = 0; j < 4; ++j) {
    gA[j] = A + (long)(m0 + w * 32 + j * 8 + r8) * K + gsw;
    gB[j] = Bt + (long)(n0 + w * 32 + j * 8 + r8) * K + gsw;
  }

  // ---- ds_read swizzled byte offsets (per-lane constant) ----
  const int kx = (l16 & 7) << 4;
  const int ko0 = (quad * 16) ^ kx;       // k-slice 0 (k=0..31)
  const int ko1 = (64 + quad * 16) ^ kx;  // k-slice 1 (k=32..63)

  f32x4 acc[8][4] = {};  // [mt][nt]

  const int nt = K >> 6;

  // ---- prologue: stage tile 0 into buf0 ----
#pragma unroll
  for (int j = 0; j < 4; ++j) {
    GLDS(gA[j], As[0] + (w * 32 + j * 8) * GBK);
    GLDS(gB[j], Bs[0] + (w * 32 + j * 8) * GBK);
  }
  asm volatile("s_waitcnt vmcnt(0)" ::: "memory");
  __builtin_amdgcn_s_barrier();

  for (int t = 0; t < nt; ++t) {
    const bf16_t* Ab = (t & 1) ? As[1] : As[0];
    const bf16_t* Bb = (t & 1) ? Bs[1] : Bs[0];
    bf16_t* Asb = (t & 1) ? As[0] : As[1];
    bf16_t* Bsb = (t & 1) ? Bs[0] : Bs[1];
    const bool pf = (t + 1 < nt);
    const long ko = (long)(t + 1) * GBK;

    const char* Arow = (const char*)Ab + (size_t)(wr * 128 + l16) * 128;
    const char* Brow = (const char*)Bb + (size_t)(wc * 64 + l16) * 128;

    bf16x8 af[4][2], bn0[2][2], bn1[2][2];

    // ---------------- phase 0: A m-half0 + B n-half0; stage j=0,1 ----------
#pragma unroll
    for (int mt = 0; mt < 4; ++mt) {
      af[mt][0] = *(const bf16x8*)(Arow + (size_t)mt * 16 * 128 + ko0);
      af[mt][1] = *(const bf16x8*)(Arow + (size_t)mt * 16 * 128 + ko1);
    }
#pragma unroll
    for (int n = 0; n < 2; ++n) {
      bn0[n][0] = *(const bf16x8*)(Brow + (size_t)n * 16 * 128 + ko0);
      bn0[n][1] = *(const bf16x8*)(Brow + (size_t)n * 16 * 128 + ko1);
    }
    if (pf) {
      GLDS(gA[0] + ko, Asb + (w * 32) * GBK);
      GLDS(gB[0] + ko, Bsb + (w * 32) * GBK);
      GLDS(gA[1] + ko, Asb + (w * 32 + 8) * GBK);
      GLDS(gB[1] + ko, Bsb + (w * 32 + 8) * GBK);
    }
    __builtin_amdgcn_s_barrier();
    __builtin_amdgcn_s_setprio(1);
#pragma unroll
    for (int mt = 0; mt < 4; ++mt)
#pragma unroll
      for (int n = 0; n < 2; ++n) {
        acc[mt][n] = MFMA32(af[mt][0], bn0[n][0], acc[mt][n]);
        acc[mt][n] = MFMA32(af[mt][1], bn0[n][1], acc[mt][n]);
      }
    __builtin_amdgcn_s_setprio(0);
    __builtin_amdgcn_s_barrier();

    // ---------------- phase 1: B n-half1; stage j=2,3 ----------------------
#pragma unroll
    for (int n = 0; n < 2; ++n) {
      bn1[n][0] = *(const bf16x8*)(Brow + (size_t)(32 + n * 16) * 128 + ko0);
      bn1[n][1] = *(const bf16x8*)(Brow + (size_t)(32 + n * 16) * 128 + ko1);
    }
    if (pf) {
      GLDS(gA[2] + ko, Asb + (w * 32 + 16) * GBK);
      GLDS(gB[2] + ko, Bsb + (w * 32 + 16) * GBK);
      GLDS(gA[3] + ko, Asb + (w * 32 + 24) * GBK);
      GLDS(gB[3] + ko, Bsb + (w * 32 + 24) * GBK);
    }
    __builtin_amdgcn_s_barrier();
    __builtin_amdgcn_s_setprio(1);
#pragma unroll
    for (int mt = 0; mt < 4; ++mt)
#pragma unroll
      for (int n = 0; n < 2; ++n) {
        acc[mt][2 + n] = MFMA32(af[mt][0], bn1[n][0], acc[mt][2 + n]);
        acc[mt][2 + n] = MFMA32(af[mt][1], bn1[n][1], acc[mt][2 + n]);
      }
    __builtin_amdgcn_s_setprio(0);
    __builtin_amdgcn_s_barrier();

    // ---------------- phase 2: A m-half1 (overwrite af) --------------------
#pragma unroll
    for (int mt = 0; mt < 4; ++mt) {
      af[mt][0] = *(const bf16x8*)(Arow + (size_t)(64 + mt * 16) * 128 + ko0);
      af[mt][1] = *(const bf16x8*)(Arow + (size_t)(64 + mt * 16) * 128 + ko1);
    }
    __builtin_amdgcn_s_barrier();
    __builtin_amdgcn_s_setprio(1);
#pragma unroll
    for (int mt = 0; mt < 4; ++mt)
#pragma unroll
      for (int n = 0; n < 2; ++n) {
        acc[4 + mt][2 + n] = MFMA32(af[mt][0], bn1[n][0], acc[4 + mt][2 + n]);
        acc[4 + mt][2 + n] = MFMA32(af[mt][1], bn1[n][1], acc[4 + mt][2 + n]);
      }
    __builtin_amdgcn_s_setprio(0);
    __builtin_amdgcn_s_barrier();

    // ---------------- phase 3: (regs only) ---------------------------------
    __builtin_amdgcn_s_setprio(1);
#pragma unroll
    for (int mt = 0; mt < 4; ++mt)
#pragma unroll
      for (int n = 0; n < 2; ++n) {
        acc[4 + mt][n] = MFMA32(af[mt][0], bn0[n][0], acc[4 + mt][n]);
        acc[4 + mt][n] = MFMA32(af[mt][1], bn0[n][1], acc[4 + mt][n]);
      }
    __builtin_amdgcn_s_setprio(0);

    // ---- K-tile boundary: staged loads landed + all waves done reading ----
    asm volatile("s_waitcnt vmcnt(0)" ::: "memory");
    __builtin_amdgcn_s_barrier();
  }

  // ---- epilogue: C-write ----
#pragma unroll
  for (int mt = 0; mt < 8; ++mt)
#pragma unroll
    for (int n = 0; n < 4; ++n) {
      const int col = n0 + wc * 64 + n * 16 + l16;
#pragma unroll
      for (int i = 0; i < 4; ++i) {
        const int row = m0 + wr * 128 + mt * 16 + quad * 4 + i;
        C[(long)row * N + col] = (bf16_t)acc[mt][n][i];
      }
    }
}

// ---------------- GEMM (m97 structure): C[M][N] = A[M][K] @ Bt[N][K]^T -------
// ratio-2.0 economics (wave tile 64x64).  Used for the out GEMM: grid (8,32)
// = 256 blocks = exactly 1 round.
#define BM 128
#define BN 128
#define BK 32

template <typename OutT>
__global__ void __launch_bounds__(256) gemm_bt(const bf16_t* __restrict__ A,
                                               const bf16_t* __restrict__ Bt,
                                               OutT* __restrict__ C, int M,
                                               int N, int K) {
  __shared__ __align__(16) bf16_t As[BM * BK];
  __shared__ __align__(16) bf16_t Bs[BN * BK];
  const int tid = threadIdx.x;
  const int w = tid >> 6;
  const int lane = tid & 63;
  const int quad = lane >> 4, l16 = lane & 15;
  const int m0 = blockIdx.y * BM, n0 = blockIdx.x * BN;
  const int wm = (w >> 1) * 64, wn = (w & 1) * 64;
  const int srow = tid >> 2;       // 0..63
  const int scol = (tid & 3) * 8;  // 0,8,16,24

  const bf16_t* Ag0 = A + (long)(m0 + srow) * K + scol;
  const bf16_t* Ag1 = Ag0 + (long)64 * K;
  const bf16_t* Bg0 = Bt + (long)(n0 + srow) * K + scol;
  const bf16_t* Bg1 = Bg0 + (long)64 * K;
  bf16_t* lA0 = As + tid * 8;  // == srow*32 + scol
  bf16_t* lA1 = As + 2048 + tid * 8;
  bf16_t* lB0 = Bs + tid * 8;
  bf16_t* lB1 = Bs + 2048 + tid * 8;

  f32x4 acc[4][4] = {};

  for (int k0 = 0; k0 < K; k0 += BK) {
    GLDS(Ag0 + k0, lA0);
    GLDS(Ag1 + k0, lA1);
    GLDS(Bg0 + k0, lB0);
    GLDS(Bg1 + k0, lB1);
    __syncthreads();
    bf16x8 af[4], bfr[4];
#pragma unroll
    for (int t = 0; t < 4; ++t) {
      af[t] = *(const bf16x8*)(As + (wm + t * 16 + l16) * BK + quad * 8);
      bfr[t] = *(const bf16x8*)(Bs + (wn + t * 16 + l16) * BK + quad * 8);
    }
#pragma unroll
    for (int mt = 0; mt < 4; ++mt)
#pragma unroll
      for (int nt = 0; nt < 4; ++nt)
        acc[mt][nt] = MFMA32(af[mt], bfr[nt], acc[mt][nt]);
    __syncthreads();
  }

#pragma unroll
  for (int mt = 0; mt < 4; ++mt)
#pragma unroll
    for (int nt = 0; nt < 4; ++nt) {
      const int col = n0 + wn + nt * 16 + l16;
#pragma unroll
      for (int i = 0; i < 4; ++i) {
        const int row = m0 + wm + mt * 16 + quad * 4 + i;
        C[(long)row * N + col] = (OutT)acc[mt][nt][i];
      }
    }
}

// ---------------- transpose v slice of proj -> vt[(b,h)][d][perm(key)] -------
// Key permutation within each 64-key window (R2-HW-verified): element j of a
// b128 at in-window offset cp*32+quad*8 is key cp*32 + (j>>2)*16 + quad*4 +
// (j&3).
__global__ void __launch_bounds__(256) transpose_v(const bf16_t* __restrict__ proj,
                                                   bf16_t* __restrict__ vt) {
  __shared__ bf16_t tile[32][34];
  const int bh = blockIdx.z;
  const int b = bh >> 4, h = bh & 15;
  const int t0 = blockIdx.x * 32, d0 = blockIdx.y * 32;
  const int tx = threadIdx.x & 31, ty = threadIdx.x >> 5;
  const bf16_t* src = proj + (long)(b * T_SEQ) * NPROJ + 4096 + h * 128;
#pragma unroll
  for (int i = 0; i < 32; i += 8)
    tile[ty + i][tx] = src[(long)(t0 + ty + i) * NPROJ + d0 + tx];
  __syncthreads();
  const int d_loc = threadIdx.x >> 3;
  const int g = threadIdx.x & 7;
  const int s = g >> 2, qd = g & 3;
  const int tl = s * 16 + qd * 4;
  bf16x4 o = {tile[tl + 0][d_loc], tile[tl + 1][d_loc], tile[tl + 2][d_loc],
              tile[tl + 3][d_loc]};
  bf16_t* dst = vt + (long)bh * (DV * T_SEQ) + (long)(d0 + d_loc) * T_SEQ;
  *(bf16x4*)(dst + t0 + qd * 8 + s * 4) = o;
}

// ---------------- attention: split-stream, PAIRED qblk (equal work) ---------
// grid: (1024). x -> p = x>>7 (pair 0..7), st = (x>>6)&1, bh = x&63.
// Phase 0: qblk=15-p, phase 1: qblk=p -> every block runs exactly 17 tiles.
// V staging: row = tid>>3 (+32j), col granule = tid&7 -> write banks
// 4((t>>3)+(t&7)) mod 32 = uniform (R15).  K staging row=tid>>2 was already
// uniform.
__global__ void __launch_bounds__(256) attn_kernel(const bf16_t* __restrict__ proj,
                                                   const bf16_t* __restrict__ vt,
                                                   _Float16* __restrict__ a1,
                                                   _Float16* __restrict__ a2) {
  const int x = blockIdx.x;
  const int p = x >> 7;
  const int st = (x >> 6) & 1;
  const int bh = x & 63;
  const int b = bh >> 4, h = bh & 15;
  const int tid = threadIdx.x;
  const int w = tid >> 6, lane = tid & 63;
  const int quad = lane >> 4, l16 = lane & 15;
  const long bT = (long)b * T_SEQ;

  __shared__ __align__(16) bf16_t Ks[64 * KSTR];  // [key][dim]
  __shared__ __align__(16) bf16_t Vs[DV * KSTR];  // [dim][perm(key)]

  const int koff = h * 64 + 2048 + st * 1024;
  const bf16_t* gK = proj + (bT + (tid >> 2)) * (long)NPROJ + koff + (tid & 3) * 16;
  const bf16_t* gV = vt + (long)bh * DV * T_SEQ + (long)(tid >> 3) * T_SEQ +
                     (tid & 7) * 8;
  const int kwK = (tid >> 2) * KSTR + (tid & 3) * 16;
  const int kwV = (tid >> 3) * KSTR + (tid & 7) * 8;

  const float sc = 0.125f * LOG2E;
  const bf16x4 one4 = {(bf16_t)1.0f, (bf16_t)1.0f, (bf16_t)1.0f, (bf16_t)1.0f};

  for (int ph = 0; ph < 2; ++ph) {
    const int qblk = ph ? p : 15 - p;
    const int q0 = qblk * 64 + w * 16;
    const int qg = q0 + l16;

    const bf16_t* qrow = proj + (bT + qg) * (long)NPROJ + h * 64 + st * 1024;
    bf16x8 aq[2];
    aq[0] = *(const bf16x8*)(qrow + quad * 8);
    aq[1] = *(const bf16x8*)(qrow + 32 + quad * 8);

    f32x4 O[8] = {};
    float m = -3.0e38f, l = 0.f;

    const int kend_blk = qblk * 64 + 64;
    const int kend_w = q0 + 16;

    bf16x8 rK[2], rV[4];
    rK[0] = *(const bf16x8*)(gK);
    rK[1] = *(const bf16x8*)(gK + 8);
#pragma unroll
    for (int j = 0; j < 4; ++j)
      rV[j] = *(const bf16x8*)(gV + (long)(32 * j) * T_SEQ);

    for (int kt = 0; kt < kend_blk; kt += 64) {
      *(bf16x8*)(Ks + kwK) = rK[0];
      *(bf16x8*)(Ks + kwK + 8) = rK[1];
#pragma unroll
      for (int j = 0; j < 4; ++j)
        *(bf16x8*)(Vs + kwV + j * 32 * KSTR) = rV[j];
      __syncthreads();

      if (kt + 64 < kend_blk) {
        const long ko = (long)(kt + 64) * NPROJ;
        rK[0] = *(const bf16x8*)(gK + ko);
        rK[1] = *(const bf16x8*)(gK + ko + 8);
#pragma unroll
        for (int j = 0; j < 4; ++j)
          rV[j] = *(const bf16x8*)(gV + kt + 64 + (long)(32 * j) * T_SEQ);
      }

      if (kt < kend_w) {
        f32x4 s[4];
#pragma unroll
        for (int c = 0; c < 4; ++c) {
          const bf16_t* kr = Ks + (c * 16 + l16) * KSTR;
          bf16x8 ka0 = *(const bf16x8*)(kr + quad * 8);
          bf16x8 ka1 = *(const bf16x8*)(kr + 32 + quad * 8);
          f32x4 z = {};
          z = MFMA32(ka0, aq[0], z);
          z = MFMA32(ka1, aq[1], z);
          s[c] = z;
        }
        if (kt + 63 > q0) {
#pragma unroll
          for (int c = 0; c < 4; ++c)
#pragma unroll
            for (int i = 0; i < 4; ++i) {
              const int key = kt + c * 16 + quad * 4 + i;
              if (key > qg) s[c][i] = -1e30f;
            }
        }
        float t[4];
#pragma unroll
        for (int c = 0; c < 4; ++c)
          t[c] = fmaxf(fmaxf(s[c][0], s[c][1]), fmaxf(s[c][2], s[c][3]));
        float mx = fmaxf(fmaxf(t[0], t[1]), fmaxf(t[2], t[3]));
        mx = fmaxf(mx, __shfl_xor(mx, 16));
        mx = fmaxf(mx, __shfl_xor(mx, 32));
        if (!__all(mx <= m + RTHR)) {
          const float mn = fmaxf(m, mx);
          const float al = exp2f((m - mn) * sc);
          m = mn;
#pragma unroll
          for (int f = 0; f < 8; ++f)
#pragma unroll
            for (int i = 0; i < 4; ++i) O[f][i] *= al;
          l *= al;
        }
        const float ms = m * sc;
        bf16x4 pc[4];
#pragma unroll
        for (int c = 0; c < 4; ++c)
#pragma unroll
          for (int i = 0; i < 4; ++i)
            pc[c][i] = (bf16_t)exp2f(fmaf(s[c][i], sc, -ms));
        f32x4 la = {};
#pragma unroll
        for (int c = 0; c < 4; ++c) la = MFMA16(one4, pc[c], la);
#pragma unroll
        for (int cp = 0; cp < 2; ++cp) {
#pragma unroll
          for (int f = 0; f < 8; ++f) {
            bf16x8 va = *(const bf16x8*)(Vs + (f * 16 + l16) * KSTR +
                                         cp * 32 + quad * 8);
            bf16x4 lo = __builtin_shufflevector(va, va, 0, 1, 2, 3);
            bf16x4 hi = __builtin_shufflevector(va, va, 4, 5, 6, 7);
            O[f] = MFMA16(lo, pc[2 * cp], O[f]);
            O[f] = MFMA16(hi, pc[2 * cp + 1], O[f]);
          }
        }
        l += la[0];
      }
      __syncthreads();
    }

    const float inv = 1.0f / l;
    _Float16* ob = st ? a2 : a1;
    _Float16* dst = ob + ((bT + qg) * 16 + h) * (long)128 + quad * 4;
#pragma unroll
    for (int f = 0; f < 8; ++f) {
      f16x4 o = {(_Float16)(O[f][0] * inv), (_Float16)(O[f][1] * inv),
                 (_Float16)(O[f][2] * inv), (_Float16)(O[f][3] * inv)};
      *(f16x4*)(dst + f * 16) = o;
    }
  }
}

// ---------------- combine: y = a1 - lam*a2, subLN(128), *(1-LI) -> bf16 ------
__global__ void __launch_bounds__(256) combine_kernel(const _Float16* __restrict__ a1,
                                                      const _Float16* __restrict__ a2,
                                                      const float* __restrict__ lamp,
                                                      bf16_t* __restrict__ yln) {
  const int unit = blockIdx.x * 4 + (threadIdx.x >> 6);  // 0..65535 = r*16+h
  const int lane = threadIdx.x & 63;
  const float lam = lamp[unit & 15];
  const long base = (long)unit * 128 + lane * 2;
  f16x2 v1 = *(const f16x2*)(a1 + base);
  f16x2 v2 = *(const f16x2*)(a2 + base);
  float y0 = (float)v1[0] - lam * (float)v2[0];
  float y1 = (float)v1[1] - lam * (float)v2[1];
  float sm = y0 + y1, sq = y0 * y0 + y1 * y1;
#pragma unroll
  for (int off = 1; off < 64; off <<= 1) {
    sm += __shfl_xor(sm, off);
    sq += __shfl_xor(sq, off);
  }
  const float mu = sm * (1.0f / 128.0f);
  const float var = sq * (1.0f / 128.0f) - mu * mu;
  const float rs = rsqrtf(var + 1e-5f) * ONE_MINUS_LI;
  bf16x2 o = {(bf16_t)((y0 - mu) * rs), (bf16_t)((y1 - mu) * rs)};
  *(bf16x2*)(yln + base) = o;
}

// ---------------------------------------------------------------------------
extern "C" void kernel_launch(void* const* d_in, const int* in_sizes, int n_in,
                              void* d_out, int out_size, void* d_ws,
                              size_t ws_size, hipStream_t stream) {
  const float* x = (const float*)d_in[0];
  const float* Wq1 = (const float*)d_in[1];
  const float* Wq2 = (const float*)d_in[2];
  const float* Wk1 = (const float*)d_in[3];
  const float* Wk2 = (const float*)d_in[4];
  const float* Wv = (const float*)d_in[5];
  const float* Wc = (const float*)d_in[6];
  const float* lq1 = (const float*)d_in[7];
  const float* lk1 = (const float*)d_in[8];
  const float* lq2 = (const float*)d_in[9];
  const float* lk2 = (const float*)d_in[10];
  float* out = (float*)d_out;

  char* ws = (char*)d_ws;
  bf16_t* wcat = (bf16_t*)(ws + OFF_WCAT);
  bf16_t* xb = (bf16_t*)(ws + OFF_XB);
  bf16_t* wct = (bf16_t*)(ws + OFF_WCT);
  bf16_t* projb = (bf16_t*)(ws + OFF_PROJ);
  bf16_t* vtb = (bf16_t*)(ws + OFF_VT);
  bf16_t* ylnb = (bf16_t*)(ws + OFF_YLN);
  float* lamp = (float*)(ws + OFF_LAM);
  _Float16* a1b = (_Float16*)(ws + OFF_YLN);   // aliases yln (in-place combine)
  _Float16* a2b = (_Float16*)(ws + OFF_WCAT);  // aliases wcat+xb (dead after proj)

  cast_x<<<4096, 256, 0, stream>>>(x, xb);
  tcast_w4<<<dim3(32, 32, 4), 256, 0, stream>>>(Wq1, Wq2, Wk1, Wk2, wcat);
  tcast_w<<<dim3(32, 64), 256, 0, stream>>>(Wv, wcat, 1024, 2048, 4096);
  tcast_w<<<dim3(64, 32), 256, 0, stream>>>(Wc, wct, 2048, 1024, 0);
  lam_kernel<<<1, 64, 0, stream>>>(lq1, lk1, lq2, lk2, lamp);

  // proj = xb @ wcat^T : M=4096 N=6144 K=1024 ; 16x24 = 384 tiles (384%8==0)
  gemm256<<<dim3(384), 512, 0, stream>>>(xb, wcat, projb, 4096, 6144, 1024, 24);
  transpose_v<<<dim3(32, 4, 64), 256, 0, stream>>>(projb, vtb);
  attn_kernel<<<dim3(1024), 256, 0, stream>>>(projb, vtb, a1b, a2b);
  combine_kernel<<<dim3(16384), 256, 0, stream>>>(a1b, a2b, lamp, ylnb);
  // out = yln @ wc^T : M=4096 N=1024 K=2048  (BN=128 -> 256 blocks, 1 round)
  gemm_bt<float><<<dim3(8, 32), 256, 0, stream>>>(ylnb, wct, out, 4096, 1024, 2048);
}

// Round 9
// 313.948 us; speedup vs baseline: 1.0615x; 1.0088x over previous
//
#include <hip/hip_runtime.h>

// ---------------------------------------------------------------------------
// DiffAttention forward, bf16 MFMA pipeline.  B=4 T=1024 C=1024 H=16 hs=64 dv=128.
//   1. cast x -> bf16; transpose-cast weights -> W^T[n][k] bf16
//   2. proj GEMM: 256x256, 8 waves (2Mx4N, wave 128x64), K32-half unit ring:
//      per phase {issue unit p+2 (4 GLDS), vmcnt(8) COUNTED, 1 barrier,
//      12 ds_read_b128, 32 MFMA}. No sched_barrier (R17), no lgkmcnt asm.
//   3. transpose v slice -> vt[(b,h)][dim][token] (plain, R3)
//   4. attention: split-stream, UNPAIRED LPT grid 2048 (exact R3 kernel,
//      74.7us measured) -> a_s = (P/l)V fp16.
//   4b. combine: y = a1 - lam_h*a2, subLN over 128, *(1-LI), bf16 -> yln.
//   5. out GEMM: gemm_bt BN=128 (256 blocks = 1 round).
// MFMA mappings (HW-verified): A[m=lane&15][k=quad*8+j] (K=32) / quad*4+j
// (K=16); B^T[n=lane&15][k=same]; C/D: col=lane&15, row=quad*4+reg.
// R8: #else of MFMA16 guard must be host-safe.
// R10 (R2): no-LDS direct-global attn regressed. Keep LDS staging.
// R13 (R5): 1-blk/CU grids pay a 1.5-round tail at 384 blocks (unavoidable
// for 384 tiles; do not re-litigate via tile-shape).
// R14 (R6): wave-tile LDS economics: mt*nt/(mt+nt) >= ~2.5. Keep 128x64.
// R16: infra failures -> resubmit identical, don't mutate blind.
// R17 (R8 post-mortem): (a) attn bank conflicts were NOT the critical path —
// the R15 remap cut them 11.1M->6.7M yet attn got SLOWER (74.7->85.2, the
// paired/permuted bundle cost VGPR 84->100, Occ 28->18). Reverted to R3 attn.
// (b) R5/R6 proj regressions re-attributed to sched_barrier(0) order-pinning
// (m141: -42%); this round's counted-vmcnt ring has NONE.
// Proj FIFO ledger (per wave; unit u = {A,B} K32-half, 4 GLDS):
//   prologue: issue u0,u1.  phase p: issue u(p+2) -> queue [u(p),u(p+1),
//   u(p+2)] = 12 loads; vmcnt(8) -> u(p) landed. Peel: p=np-2 vmcnt(4),
//   p=np-1 vmcnt(0).  LDS region of u(p+2) == region of u(p-2) (cycle 4);
//   its readers ran in phase p-2, and the issuing wave has passed barrier
//   p-1 => all waves completed phase p-2 body. Race-free with 1 barrier/ph.
// ---------------------------------------------------------------------------

#define T_SEQ 1024
#define NH 16
#define DV 128
#define NPROJ 6144
#define KSTR 72  // attn K/V LDS row stride (elements)

typedef __bf16 bf16_t;
typedef __bf16 bf16x8 __attribute__((ext_vector_type(8)));
typedef __bf16 bf16x4 __attribute__((ext_vector_type(4)));
typedef __bf16 bf16x2 __attribute__((ext_vector_type(2)));
typedef _Float16 f16x4 __attribute__((ext_vector_type(4)));
typedef _Float16 f16x2 __attribute__((ext_vector_type(2)));
typedef short s16x4 __attribute__((ext_vector_type(4)));
typedef float f32x4 __attribute__((ext_vector_type(4)));

#define LAMBDA_INIT 0.35550906759096928f
#define ONE_MINUS_LI 0.6444909324090307f
#define LOG2E 1.4426950408889634f
// defer-rescale threshold in RAW score units: 8 / (0.125*log2e) ~= 44.36
#define RTHR 44.36f

#if __has_builtin(__builtin_amdgcn_mfma_f32_16x16x16_bf16)
#define MFMA16(a, b, c) __builtin_amdgcn_mfma_f32_16x16x16_bf16(a, b, c, 0, 0, 0)
#elif __has_builtin(__builtin_amdgcn_mfma_f32_16x16x16bf16_1k)
#define MFMA16(a, b, c)                                                       \
  __builtin_amdgcn_mfma_f32_16x16x16bf16_1k(                                  \
      __builtin_bit_cast(s16x4, a), __builtin_bit_cast(s16x4, b), c, 0, 0, 0)
#else
#define MFMA16(a, b, c) (c)  // host pass only — never executed
#endif

#define MFMA32(a, b, c) __builtin_amdgcn_mfma_f32_16x16x32_bf16(a, b, c, 0, 0, 0)

// async global->LDS, 16B/lane.
#define GLDS(g, l)                                                            \
  __builtin_amdgcn_global_load_lds(                                           \
      (const __attribute__((address_space(1))) void*)(g),                     \
      (__attribute__((address_space(3))) void*)(l), 16, 0, 0)

// ---------------- workspace layout (bytes) ----------------
static const size_t OFF_WCAT = 0;                                  // 6144x1024 bf16
static const size_t OFF_XB = OFF_WCAT + (size_t)6144 * 1024 * 2;   // 4096x1024 bf16
static const size_t OFF_WCT = OFF_XB + (size_t)4096 * 1024 * 2;    // 1024x2048 bf16
static const size_t OFF_PROJ = OFF_WCT + (size_t)2048 * 1024 * 2;  // 4096x6144 bf16
static const size_t OFF_VT = OFF_PROJ + (size_t)4096 * 6144 * 2;   // 64*128*1024 bf16
static const size_t OFF_YLN = OFF_VT + (size_t)64 * 128 * 1024 * 2;// 4096x2048 bf16
static const size_t OFF_LAM = OFF_YLN + (size_t)4096 * 2048 * 2;   // 16 f32
// a1 (fp16, 16.78 MB) aliases YLN (combine rewrites in place); a2 aliases
// WCAT+XB (dead after proj GEMM).

// ---------------- elementwise cast x -> bf16 ----------------
__global__ void __launch_bounds__(256) cast_x(const float* __restrict__ x,
                                              bf16_t* __restrict__ o) {
  const int i = (blockIdx.x * 256 + threadIdx.x) * 4;
  float4 v = *(const float4*)(x + i);
  bf16x4 r = {(bf16_t)v.x, (bf16_t)v.y, (bf16_t)v.z, (bf16_t)v.w};
  *(bf16x4*)(o + i) = r;
}

// ---------------- transpose-cast weight W[K][N] fp32 -> Wt[row0+n][k] bf16 ----
__device__ __forceinline__ void tcast_body(const float* __restrict__ W,
                                           bf16_t* __restrict__ Wt, int K,
                                           int N, int row0) {
  __shared__ float tile[32][33];
  const int k0 = blockIdx.x * 32, n0 = blockIdx.y * 32;
  const int tx = threadIdx.x & 31, ty = threadIdx.x >> 5;  // 32x8
#pragma unroll
  for (int i = 0; i < 32; i += 8)
    tile[ty + i][tx] = W[(long)(k0 + ty + i) * N + n0 + tx];
  __syncthreads();
#pragma unroll
  for (int i = 0; i < 32; i += 8)
    Wt[(long)(row0 + n0 + ty + i) * K + k0 + tx] = (bf16_t)tile[tx][ty + i];
}

__global__ void __launch_bounds__(256) tcast_w(const float* __restrict__ W,
                                               bf16_t* __restrict__ Wt, int K,
                                               int N, int row0) {
  tcast_body(W, Wt, K, N, row0);
}

// fused: the four 1024x1024 q/k weights in one launch (z selects)
__global__ void __launch_bounds__(256) tcast_w4(const float* __restrict__ W0,
                                                const float* __restrict__ W1,
                                                const float* __restrict__ W2,
                                                const float* __restrict__ W3,
                                                bf16_t* __restrict__ Wt) {
  const float* Ws[4] = {W0, W1, W2, W3};
  tcast_body(Ws[blockIdx.z], Wt, 1024, 1024, blockIdx.z * 1024);
}

// ---------------- per-head lambda ----------------
__global__ void lam_kernel(const float* __restrict__ lq1,
                           const float* __restrict__ lk1,
                           const float* __restrict__ lq2,
                           const float* __restrict__ lk2,
                           float* __restrict__ lam) {
  const int h = threadIdx.x;
  if (h < NH) {
    float d1 = 0.f, d2 = 0.f;
    for (int i = 0; i < 64; ++i) {
      d1 += lq1[h * 64 + i] * lk1[h * 64 + i];
      d2 += lq2[h * 64 + i] * lk2[h * 64 + i];
    }
    lam[h] = expf(d1) - expf(d2) + LAMBDA_INIT;
  }
}

// ---------------- proj GEMM: 256x256, K32-half ring, counted vmcnt(8) -------
// C[M][N] bf16 = A[M][K] @ Bt[N][K]^T.  See header ledger for the schedule.
// Swizzle (64B rows, 4 granules): stored granule g holds source granule
// g^(row&3); reads use byte (row*64 + ((quad^(l16&3))*16)).
#define GBM 256
#define GBN 256

__global__ void __launch_bounds__(512, 1) gemm256(const bf16_t* __restrict__ A,
                                                  const bf16_t* __restrict__ Bt,
                                                  bf16_t* __restrict__ C,
                                                  int M, int N, int K,
                                                  int nbx) {
  __shared__ __align__(16) bf16_t As[2][2][256 * 32];  // [dbuf][khalf]
  __shared__ __align__(16) bf16_t Bs[2][2][256 * 32];
  const int tid = threadIdx.x;
  const int w = tid >> 6, lane = tid & 63;
  const int quad = lane >> 4, l16 = lane & 15;
  const int wr = w >> 2, wc = w & 3;  // 2M x 4N wave grid; wave tile 128x64

  // ---- bijective XCD swizzle (grid % 8 == 0) ----
  const int wg = blockIdx.x;
  const int cpx = gridDim.x >> 3;
  const int sw = (wg & 7) * cpx + (wg >> 3);
  const int by = sw / nbx, bx = sw % nbx;
  const int m0 = by * GBM, n0 = bx * GBN;

  // ---- staging source: lane covers (row = pass*128 + tid>>2, g = tid&3),
  //      source granule = g ^ (row&3)  (row&3 == (tid>>2)&3 for both passes)
  const int srow = tid >> 2;                      // 0..127
  const int sg = (tid & 3) ^ (srow & 3);          // swizzled granule
  const bf16_t* gA = A + (long)(m0 + srow) * K + sg * 8;
  const bf16_t* gB = Bt + (long)(n0 + srow) * K + sg * 8;

// issue stage-unit u = {A,B} K32-half of tile u>>1 (4 GLDS, 16KB each matrix)
#define ISSUE_UNIT(u)                                                         \
  {                                                                           \
    const int tu_ = (u) >> 1, hu_ = (u) & 1, bu_ = tu_ & 1;                   \
    const long ku_ = (long)tu_ * 64 + hu_ * 32;                               \
    bf16_t* da_ = &As[bu_][hu_][0] + w * 16 * 32;                             \
    bf16_t* db_ = &Bs[bu_][hu_][0] + w * 16 * 32;                             \
    GLDS(gA + ku_, da_);                                                      \
    GLDS(gA + (long)128 * K + ku_, da_ + 128 * 32);                           \
    GLDS(gB + ku_, db_);                                                      \
    GLDS(gB + (long)128 * K + ku_, db_ + 128 * 32);                           \
  }

  const int kq = (quad ^ (l16 & 3)) * 16;  // swizzled read byte offset

#define PHASE_BODY(p)                                                         \
  {                                                                           \
    const char* Ab_ = (const char*)&As[((p) >> 1) & 1][(p)&1][0];             \
    const char* Bb_ = (const char*)&Bs[((p) >> 1) & 1][(p)&1][0];             \
    bf16x8 af_[8], bf_[4];                                                    \
    _Pragma("unroll") for (int mt_ = 0; mt_ < 8; ++mt_)                       \
        af_[mt_] = *(const bf16x8*)(Ab_ +                                     \
                                    (size_t)(wr * 128 + mt_ * 16 + l16) * 64 +\
                                    kq);                                      \
    _Pragma("unroll") for (int n_ = 0; n_ < 4; ++n_)                          \
        bf_[n_] = *(const bf16x8*)(Bb_ +                                      \
                                   (size_t)(wc * 64 + n_ * 16 + l16) * 64 +   \
                                   kq);                                       \
    __builtin_amdgcn_s_setprio(1);                                            \
    _Pragma("unroll") for (int mt_ = 0; mt_ < 8; ++mt_)                       \
        _Pragma("unroll") for (int n_ = 0; n_ < 4; ++n_)                      \
            acc[mt_][n_] = MFMA32(af_[mt_], bf_[n_], acc[mt_][n_]);           \
    __builtin_amdgcn_s_setprio(0);                                            \
  }

  f32x4 acc[8][4] = {};
  const int np = K >> 5;  // 32 phases for K=1024

  ISSUE_UNIT(0);
  ISSUE_UNIT(1);
  for (int p = 0; p < np - 2; ++p) {
    ISSUE_UNIT(p + 2);
    asm volatile("s_waitcnt vmcnt(8)" ::: "memory");
    __builtin_amdgcn_s_barrier();
    PHASE_BODY(p);
  }
  asm volatile("s_waitcnt vmcnt(4)" ::: "memory");
  __builtin_amdgcn_s_barrier();
  PHASE_BODY(np - 2);
  asm volatile("s_waitcnt vmcnt(0)" ::: "memory");
  __builtin_amdgcn_s_barrier();
  PHASE_BODY(np - 1);

#undef ISSUE_UNIT
#undef PHASE_BODY

  // ---- epilogue: C-write ----
#pragma unroll
  for (int mt = 0; mt < 8; ++mt)
#pragma unroll
    for (int n = 0; n < 4; ++n) {
      const int col = n0 + wc * 64 + n * 16 + l16;
#pragma unroll
      for (int i = 0; i < 4; ++i) {
        const int row = m0 + wr * 128 + mt * 16 + quad * 4 + i;
        C[(long)row * N + col] = (bf16_t)acc[mt][n][i];
      }
    }
}

// ---------------- GEMM (m97 structure): C[M][N] = A[M][K] @ Bt[N][K]^T -------
// ratio-2.0 economics (wave tile 64x64).  Used for the out GEMM: grid (8,32)
// = 256 blocks = exactly 1 round.
#define BM 128
#define BN 128
#define BK 32

template <typename OutT>
__global__ void __launch_bounds__(256) gemm_bt(const bf16_t* __restrict__ A,
                                               const bf16_t* __restrict__ Bt,
                                               OutT* __restrict__ C, int M,
                                               int N, int K) {
  __shared__ __align__(16) bf16_t As[BM * BK];
  __shared__ __align__(16) bf16_t Bs[BN * BK];
  const int tid = threadIdx.x;
  const int w = tid >> 6;
  const int lane = tid & 63;
  const int quad = lane >> 4, l16 = lane & 15;
  const int m0 = blockIdx.y * BM, n0 = blockIdx.x * BN;
  const int wm = (w >> 1) * 64, wn = (w & 1) * 64;
  const int srow = tid >> 2;       // 0..63
  const int scol = (tid & 3) * 8;  // 0,8,16,24

  const bf16_t* Ag0 = A + (long)(m0 + srow) * K + scol;
  const bf16_t* Ag1 = Ag0 + (long)64 * K;
  const bf16_t* Bg0 = Bt + (long)(n0 + srow) * K + scol;
  const bf16_t* Bg1 = Bg0 + (long)64 * K;
  bf16_t* lA0 = As + tid * 8;  // == srow*32 + scol
  bf16_t* lA1 = As + 2048 + tid * 8;
  bf16_t* lB0 = Bs + tid * 8;
  bf16_t* lB1 = Bs + 2048 + tid * 8;

  f32x4 acc[4][4] = {};

  for (int k0 = 0; k0 < K; k0 += BK) {
    GLDS(Ag0 + k0, lA0);
    GLDS(Ag1 + k0, lA1);
    GLDS(Bg0 + k0, lB0);
    GLDS(Bg1 + k0, lB1);
    __syncthreads();
    bf16x8 af[4], bfr[4];
#pragma unroll
    for (int t = 0; t < 4; ++t) {
      af[t] = *(const bf16x8*)(As + (wm + t * 16 + l16) * BK + quad * 8);
      bfr[t] = *(const bf16x8*)(Bs + (wn + t * 16 + l16) * BK + quad * 8);
    }
#pragma unroll
    for (int mt = 0; mt < 4; ++mt)
#pragma unroll
      for (int nt = 0; nt < 4; ++nt)
        acc[mt][nt] = MFMA32(af[mt], bfr[nt], acc[mt][nt]);
    __syncthreads();
  }

#pragma unroll
  for (int mt = 0; mt < 4; ++mt)
#pragma unroll
    for (int nt = 0; nt < 4; ++nt) {
      const int col = n0 + wn + nt * 16 + l16;
#pragma unroll
      for (int i = 0; i < 4; ++i) {
        const int row = m0 + wm + mt * 16 + quad * 4 + i;
        C[(long)row * N + col] = (OutT)acc[mt][nt][i];
      }
    }
}

// ---------------- transpose v slice of proj -> vt[(b,h)][d][t] (plain, R3) ---
__global__ void __launch_bounds__(256) transpose_v(const bf16_t* __restrict__ proj,
                                                   bf16_t* __restrict__ vt) {
  __shared__ bf16_t tile[32][34];
  const int bh = blockIdx.z;
  const int b = bh >> 4, h = bh & 15;
  const int t0 = blockIdx.x * 32, d0 = blockIdx.y * 32;
  const int tx = threadIdx.x & 31, ty = threadIdx.x >> 5;
  const bf16_t* src = proj + (long)(b * T_SEQ) * NPROJ + 4096 + h * 128;
#pragma unroll
  for (int i = 0; i < 32; i += 8)
    tile[ty + i][tx] = src[(long)(t0 + ty + i) * NPROJ + d0 + tx];
  __syncthreads();
  bf16_t* dst = vt + ((long)bh * DV) * T_SEQ;
#pragma unroll
  for (int i = 0; i < 32; i += 8)
    dst[(long)(d0 + ty + i) * T_SEQ + t0 + tx] = tile[tx][ty + i];
}

// ---------------- attention: split-stream, one (qblk, stream) per block ------
// EXACT R3 kernel (74.7us measured).  grid: (2048). x>>7 = qi (qblk = 15-qi,
// big first / LPT), st = (x>>6)&1, bh = x&63 (x%8 tracks bh -> same-(b,h)
// blocks share an XCD's L2).  4 waves; wave w owns q rows q0..q0+15.
__global__ void __launch_bounds__(256) attn_kernel(const bf16_t* __restrict__ proj,
                                                   const bf16_t* __restrict__ vt,
                                                   _Float16* __restrict__ a1,
                                                   _Float16* __restrict__ a2) {
  const int x = blockIdx.x;
  const int qblk = 15 - (x >> 7);
  const int st = (x >> 6) & 1;
  const int bh = x & 63;
  const int b = bh >> 4, h = bh & 15;
  const int tid = threadIdx.x;
  const int w = tid >> 6, lane = tid & 63;
  const int quad = lane >> 4, l16 = lane & 15;
  const long bT = (long)b * T_SEQ;

  __shared__ __align__(16) bf16_t Ks[64 * KSTR];  // [key][dim]
  __shared__ __align__(16) bf16_t Vs[DV * KSTR];  // [dim][key]

  // ---- staging source pointers (this stream's K; shared V) ----
  const int koff = h * 64 + 2048 + st * 1024;
  const bf16_t* gK = proj + (bT + (tid >> 2)) * (long)NPROJ + koff + (tid & 3) * 16;
  const bf16_t* gV = vt + (long)bh * DV * T_SEQ + (long)(tid >> 1) * T_SEQ +
                     (tid & 1) * 32;
  const int kwK = (tid >> 2) * KSTR + (tid & 3) * 16;
  const int kwV = (tid >> 1) * KSTR + (tid & 1) * 32;

  const float sc = 0.125f * LOG2E;  // 1/sqrt(64) folded with log2(e)
  const int q0 = qblk * 64 + w * 16;
  const int qg = q0 + l16;  // this lane's q row (all fragments)

  // ---- Q fragments (B-operand role), this stream only ----
  const bf16_t* qrow = proj + (bT + qg) * (long)NPROJ + h * 64 + st * 1024;
  bf16x8 aq[2];
  aq[0] = *(const bf16x8*)(qrow + quad * 8);
  aq[1] = *(const bf16x8*)(qrow + 32 + quad * 8);

  f32x4 O[8] = {};  // O^T[d=f*16+quad*4+reg][q=l16]
  float m = -3.0e38f, l = 0.f;
  const bf16x4 one4 = {(bf16_t)1.0f, (bf16_t)1.0f, (bf16_t)1.0f, (bf16_t)1.0f};

  const int kend_blk = qblk * 64 + 64;
  const int kend_w = q0 + 16;

  // ---- prime the register pipeline with tile kt=0 ----
  bf16x8 rK[2], rV[4];
  rK[0] = *(const bf16x8*)(gK);
  rK[1] = *(const bf16x8*)(gK + 8);
#pragma unroll
  for (int j = 0; j < 4; ++j) rV[j] = *(const bf16x8*)(gV + j * 8);

  for (int kt = 0; kt < kend_blk; kt += 64) {
    // ---- commit staged registers to LDS ----
    *(bf16x8*)(Ks + kwK) = rK[0];
    *(bf16x8*)(Ks + kwK + 8) = rK[1];
#pragma unroll
    for (int j = 0; j < 4; ++j) *(bf16x8*)(Vs + kwV + j * 8) = rV[j];
    __syncthreads();

    // ---- prefetch next tile into registers (overlaps compute) ----
    if (kt + 64 < kend_blk) {
      const long ko = (long)(kt + 64) * NPROJ;
      rK[0] = *(const bf16x8*)(gK + ko);
      rK[1] = *(const bf16x8*)(gK + ko + 8);
#pragma unroll
      for (int j = 0; j < 4; ++j)
        rV[j] = *(const bf16x8*)(gV + kt + 64 + j * 8);
    }

    if (kt < kend_w) {
      // ---- S^T = K Q^T : A=K-frag (from LDS), B=Q-frag (regs) ----
      f32x4 s[4];
#pragma unroll
      for (int c = 0; c < 4; ++c) {
        const bf16_t* kr = Ks + (c * 16 + l16) * KSTR;
        bf16x8 ka0 = *(const bf16x8*)(kr + quad * 8);
        bf16x8 ka1 = *(const bf16x8*)(kr + 32 + quad * 8);
        f32x4 z = {};
        z = MFMA32(ka0, aq[0], z);
        z = MFMA32(ka1, aq[1], z);
        s[c] = z;
      }
      // ---- causal mask (diagonal tile only) + in-lane TREE max ----
      if (kt + 63 > q0) {
#pragma unroll
        for (int c = 0; c < 4; ++c)
#pragma unroll
          for (int i = 0; i < 4; ++i) {
            const int key = kt + c * 16 + quad * 4 + i;
            if (key > qg) s[c][i] = -1e30f;
          }
      }
      float t[4];
#pragma unroll
      for (int c = 0; c < 4; ++c)
        t[c] = fmaxf(fmaxf(s[c][0], s[c][1]), fmaxf(s[c][2], s[c][3]));
      float mx = fmaxf(fmaxf(t[0], t[1]), fmaxf(t[2], t[3]));
      mx = fmaxf(mx, __shfl_xor(mx, 16));
      mx = fmaxf(mx, __shfl_xor(mx, 32));
      // ---- defer-rescale (T13) ----
      if (!__all(mx <= m + RTHR)) {
        const float mn = fmaxf(m, mx);
        const float al = exp2f((m - mn) * sc);
        m = mn;
#pragma unroll
        for (int f = 0; f < 8; ++f)
#pragma unroll
          for (int i = 0; i < 4; ++i) O[f][i] *= al;
        l *= al;
      }
      // ---- P = exp2(fma(s,sc,-m*sc)), packed bf16x4 per c ----
      const float ms = m * sc;
      bf16x4 pc[4];
#pragma unroll
      for (int c = 0; c < 4; ++c)
#pragma unroll
        for (int i = 0; i < 4; ++i)
          pc[c][i] = (bf16_t)exp2f(fmaf(s[c][i], sc, -ms));
      // ---- row-sum l via ones-row MFMA ----
      f32x4 la = {};
#pragma unroll
      for (int c = 0; c < 4; ++c) la = MFMA16(one4, pc[c], la);
      // ---- PV: O^T += V^T P^T ----
#pragma unroll
      for (int c = 0; c < 4; ++c) {
#pragma unroll
        for (int f = 0; f < 8; ++f) {
          bf16x4 va =
              *(const bf16x4*)(Vs + (f * 16 + l16) * KSTR + c * 16 + quad * 4);
          O[f] = MFMA16(va, pc[c], O[f]);
        }
      }
      l += la[0];
    }
    __syncthreads();
  }

  // ---- normalize and store per-stream a_s = (P/l)V as fp16 ----
  const float inv = 1.0f / l;
  _Float16* ob = st ? a2 : a1;
  _Float16* dst = ob + ((bT + qg) * 16 + h) * (long)128 + quad * 4;
#pragma unroll
  for (int f = 0; f < 8; ++f) {
    f16x4 o = {(_Float16)(O[f][0] * inv), (_Float16)(O[f][1] * inv),
               (_Float16)(O[f][2] * inv), (_Float16)(O[f][3] * inv)};
    *(f16x4*)(dst + f * 16) = o;
  }
}

// ---------------- combine: y = a1 - lam*a2, subLN(128), *(1-LI) -> bf16 ------
__global__ void __launch_bounds__(256) combine_kernel(const _Float16* __restrict__ a1,
                                                      const _Float16* __restrict__ a2,
                                                      const float* __restrict__ lamp,
                                                      bf16_t* __restrict__ yln) {
  const int unit = blockIdx.x * 4 + (threadIdx.x >> 6);  // 0..65535 = r*16+h
  const int lane = threadIdx.x & 63;
  const float lam = lamp[unit & 15];
  const long base = (long)unit * 128 + lane * 2;
  f16x2 v1 = *(const f16x2*)(a1 + base);
  f16x2 v2 = *(const f16x2*)(a2 + base);
  float y0 = (float)v1[0] - lam * (float)v2[0];
  float y1 = (float)v1[1] - lam * (float)v2[1];
  float sm = y0 + y1, sq = y0 * y0 + y1 * y1;
#pragma unroll
  for (int off = 1; off < 64; off <<= 1) {
    sm += __shfl_xor(sm, off);
    sq += __shfl_xor(sq, off);
  }
  const float mu = sm * (1.0f / 128.0f);
  const float var = sq * (1.0f / 128.0f) - mu * mu;
  const float rs = rsqrtf(var + 1e-5f) * ONE_MINUS_LI;
  bf16x2 o = {(bf16_t)((y0 - mu) * rs), (bf16_t)((y1 - mu) * rs)};
  *(bf16x2*)(yln + base) = o;
}

// ---------------------------------------------------------------------------
extern "C" void kernel_launch(void* const* d_in, const int* in_sizes, int n_in,
                              void* d_out, int out_size, void* d_ws,
                              size_t ws_size, hipStream_t stream) {
  const float* x = (const float*)d_in[0];
  const float* Wq1 = (const float*)d_in[1];
  const float* Wq2 = (const float*)d_in[2];
  const float* Wk1 = (const float*)d_in[3];
  const float* Wk2 = (const float*)d_in[4];
  const float* Wv = (const float*)d_in[5];
  const float* Wc = (const float*)d_in[6];
  const float* lq1 = (const float*)d_in[7];
  const float* lk1 = (const float*)d_in[8];
  const float* lq2 = (const float*)d_in[9];
  const float* lk2 = (const float*)d_in[10];
  float* out = (float*)d_out;

  char* ws = (char*)d_ws;
  bf16_t* wcat = (bf16_t*)(ws + OFF_WCAT);
  bf16_t* xb = (bf16_t*)(ws + OFF_XB);
  bf16_t* wct = (bf16_t*)(ws + OFF_WCT);
  bf16_t* projb = (bf16_t*)(ws + OFF_PROJ);
  bf16_t* vtb = (bf16_t*)(ws + OFF_VT);
  bf16_t* ylnb = (bf16_t*)(ws + OFF_YLN);
  float* lamp = (float*)(ws + OFF_LAM);
  _Float16* a1b = (_Float16*)(ws + OFF_YLN);   // aliases yln (in-place combine)
  _Float16* a2b = (_Float16*)(ws + OFF_WCAT);  // aliases wcat+xb (dead after proj)

  cast_x<<<4096, 256, 0, stream>>>(x, xb);
  tcast_w4<<<dim3(32, 32, 4), 256, 0, stream>>>(Wq1, Wq2, Wk1, Wk2, wcat);
  tcast_w<<<dim3(32, 64), 256, 0, stream>>>(Wv, wcat, 1024, 2048, 4096);
  tcast_w<<<dim3(64, 32), 256, 0, stream>>>(Wc, wct, 2048, 1024, 0);
  lam_kernel<<<1, 64, 0, stream>>>(lq1, lk1, lq2, lk2, lamp);

  // proj = xb @ wcat^T : M=4096 N=6144 K=1024 ; 16x24 = 384 tiles (384%8==0)
  gemm256<<<dim3(384), 512, 0, stream>>>(xb, wcat, projb, 4096, 6144, 1024, 24);
  transpose_v<<<dim3(32, 4, 64), 256, 0, stream>>>(projb, vtb);
  attn_kernel<<<dim3(2048), 256, 0, stream>>>(projb, vtb, a1b, a2b);
  combine_kernel<<<dim3(16384), 256, 0, stream>>>(a1b, a2b, lamp, ylnb);
  // out = yln @ wc^T : M=4096 N=1024 K=2048  (BN=128 -> 256 blocks, 1 round)
  gemm_bt<float><<<dim3(8, 32), 256, 0, stream>>>(ylnb, wct, out, 4096, 1024, 2048);
}